// Round 2
// baseline (756.402 us; speedup 1.0000x reference)
//
#include <hip/hip_runtime.h>

#define NN 131072   // total nodes (256 graphs x 512)
#define NE 1048576  // edges
// ws layout (bytes); total = 0x4701000 (~74.5 MB). hn lives in d_out (67 MB fp32).
#define OFF_DEG_OUT   0x000000
#define OFF_DEG_IN    0x080000
#define OFF_CURSOR    0x100000
#define OFF_COUNTER   0x180000
#define OFF_ROWSTART  0x181000
#define OFF_NRM_SRC   0x201000
#define OFF_NRM_DST   0x281000
#define OFF_CSR       0x301000   // int [NE]  (4 MB)
#define OFF_AGG       0x701000   // fp32 [NN][128] (67 MB)

__global__ __launch_bounds__(256) void k_count(const int* __restrict__ src,
                                               const int* __restrict__ dst,
                                               int* __restrict__ deg_out,
                                               int* __restrict__ deg_in) {
    int e = blockIdx.x * 256 + threadIdx.x;
    atomicAdd(&deg_out[src[e]], 1);
    atomicAdd(&deg_in[dst[e]], 1);
}

// per-node CSR segment reservation: wave-level scan + one atomic per wave
__global__ __launch_bounds__(256) void k_reserve(const int* __restrict__ deg_in,
                                                 const int* __restrict__ deg_out,
                                                 int* __restrict__ row_start,
                                                 float* __restrict__ nrm_src,
                                                 float* __restrict__ nrm_dst,
                                                 int* __restrict__ counter) {
    int n = blockIdx.x * 256 + threadIdx.x;
    int lane = threadIdx.x & 63;
    int di = deg_in[n];
    int dq = deg_out[n];
    nrm_dst[n] = rsqrtf((float)(di > 1 ? di : 1));
    nrm_src[n] = rsqrtf((float)(dq > 1 ? dq : 1));
    int x = di;
    #pragma unroll
    for (int off = 1; off < 64; off <<= 1) {
        int v = __shfl_up(x, off, 64);
        if (lane >= off) x += v;
    }
    int base = 0;
    if (lane == 63) base = atomicAdd(counter, x);
    base = __shfl(base, 63, 64);
    row_start[n] = base + x - di;   // exclusive within wave
}

__global__ __launch_bounds__(256) void k_fill(const int* __restrict__ src,
                                              const int* __restrict__ dst,
                                              const int* __restrict__ row_start,
                                              int* __restrict__ cursor,
                                              int* __restrict__ csr) {
    int e = blockIdx.x * 256 + threadIdx.x;
    int d = dst[e];
    int pos = atomicAdd(&cursor[d], 1);
    csr[row_start[d] + pos] = src[e];
}

// aggregation: 32 lanes per node, each lane owns 4 contiguous fp32 columns (float4)
__global__ __launch_bounds__(256) void k_agg(const float4* __restrict__ hn,
                                             const int* __restrict__ csr,
                                             const int* __restrict__ row_start,
                                             const int* __restrict__ deg_in,
                                             const float* __restrict__ nrm_dst,
                                             float4* __restrict__ agg) {
    int g = threadIdx.x >> 5;
    int lane = threadIdx.x & 31;
    int n = blockIdx.x * 8 + g;
    int rs = row_start[n];
    int cnt = deg_in[n];
    float a0 = 0.f, a1 = 0.f, a2 = 0.f, a3 = 0.f;
    for (int i = 0; i < cnt; ++i) {
        int s = csr[rs + i];
        float4 v = hn[s * 32 + lane];
        a0 += v.x; a1 += v.y; a2 += v.z; a3 += v.w;
    }
    float nd = nrm_dst[n];
    agg[n * 32 + lane] = make_float4(a0 * nd, a1 * nd, a2 * nd, a3 * nd);
}

// C[NN x 128] = relu(A[NN x 128] @ W[128 x 128] + b); epilogue *nrm_src unless last
// BM=64, BN=128, BK=32; 256 threads; 4x8 register tile per thread
__global__ __launch_bounds__(256) void k_gemm128(const float* __restrict__ A,
                                                 const float* __restrict__ W,
                                                 const float* __restrict__ bias,
                                                 const float* __restrict__ nrm,
                                                 float* __restrict__ Out,
                                                 int last) {
    __shared__ float As[64][36];
    __shared__ float Ws[32][132];
    int tid = threadIdx.x;
    int m0 = blockIdx.x * 64;
    int tm = tid >> 4, tn = tid & 15;
    float acc[4][8];
    #pragma unroll
    for (int i = 0; i < 4; ++i)
        #pragma unroll
        for (int j = 0; j < 8; ++j) acc[i][j] = 0.f;

    for (int kt = 0; kt < 128; kt += 32) {
        __syncthreads();
        // stage A tile: 64x32 fp32 = 512 float4
        #pragma unroll
        for (int r = 0; r < 2; ++r) {
            int idx = r * 256 + tid;
            int m = idx >> 3, q = idx & 7;
            float4 v = *(const float4*)&A[(m0 + m) * 128 + kt + q * 4];
            *(float4*)&As[m][q * 4] = v;
        }
        // stage W tile: 32x128 fp32 = 1024 float4
        #pragma unroll
        for (int r = 0; r < 4; ++r) {
            int idx = r * 256 + tid;
            int kk = idx >> 5, j4 = idx & 31;
            float4 v = *(const float4*)&W[(kt + kk) * 128 + j4 * 4];
            *(float4*)&Ws[kk][j4 * 4] = v;
        }
        __syncthreads();
        #pragma unroll
        for (int k4 = 0; k4 < 8; ++k4) {
            float4 av[4];
            #pragma unroll
            for (int i = 0; i < 4; ++i)
                av[i] = *(const float4*)&As[tm * 4 + i][k4 * 4];
            #pragma unroll
            for (int kk = 0; kk < 4; ++kk) {
                float4 b0 = *(const float4*)&Ws[k4 * 4 + kk][tn * 8];
                float4 b1 = *(const float4*)&Ws[k4 * 4 + kk][tn * 8 + 4];
                #pragma unroll
                for (int i = 0; i < 4; ++i) {
                    float a = ((const float*)&av[i])[kk];
                    acc[i][0] += a * b0.x; acc[i][1] += a * b0.y;
                    acc[i][2] += a * b0.z; acc[i][3] += a * b0.w;
                    acc[i][4] += a * b1.x; acc[i][5] += a * b1.y;
                    acc[i][6] += a * b1.z; acc[i][7] += a * b1.w;
                }
            }
        }
    }
    float bv[8];
    #pragma unroll
    for (int j = 0; j < 8; ++j) bv[j] = bias[tn * 8 + j];
    #pragma unroll
    for (int i = 0; i < 4; ++i) {
        int n = m0 + tm * 4 + i;
        float ns = last ? 1.0f : nrm[n];
        float4 o0, o1;
        float v[8];
        #pragma unroll
        for (int j = 0; j < 8; ++j) {
            float t = acc[i][j] + bv[j];
            t = t > 0.f ? t : 0.f;
            v[j] = t * ns;
        }
        o0 = make_float4(v[0], v[1], v[2], v[3]);
        o1 = make_float4(v[4], v[5], v[6], v[7]);
        *(float4*)&Out[n * 128 + tn * 8] = o0;
        *(float4*)&Out[n * 128 + tn * 8 + 4] = o1;
    }
}

// hn0 = (x @ W_init) * nrm_src ; x: [NN][74] fp32, W: [74][128] fp32; K padded to 76
__global__ __launch_bounds__(256) void k_gemm_init(const float* __restrict__ X,
                                                   const float* __restrict__ W,
                                                   const float* __restrict__ nrm,
                                                   float* __restrict__ hn) {
    __shared__ float As[64][80];
    __shared__ float Ws[76][132];
    int tid = threadIdx.x;
    int m0 = blockIdx.x * 64;
    int tm = tid >> 4, tn = tid & 15;
    // stage X rows: 64 x 74 fp32 = 2368 float2 (row byte offset 296*m -> 8B aligned)
    for (int idx = tid; idx < 2368; idx += 256) {
        int m = idx / 37, t = idx - m * 37;
        float2 v = *(const float2*)&X[(m0 + m) * 74 + t * 2];
        As[m][t * 2]     = v.x;
        As[m][t * 2 + 1] = v.y;
    }
    for (int idx = tid; idx < 64 * 6; idx += 256) {   // zero K-pad cols 74..79
        int m = idx / 6, c = 74 + idx % 6;
        As[m][c] = 0.f;
    }
    // stage W: 74 x 128 fp32 = 2368 float4
    for (int idx = tid; idx < 2368; idx += 256) {
        int kk = idx >> 5, j4 = idx & 31;
        float4 v = *(const float4*)&W[kk * 128 + j4 * 4];
        *(float4*)&Ws[kk][j4 * 4] = v;
    }
    {   // zero W pad rows 74,75 (avoid 0 * garbage from uninit LDS)
        int kk = 74 + (tid >> 7), j = tid & 127;
        Ws[kk][j] = 0.f;
    }
    __syncthreads();
    float acc[4][8];
    #pragma unroll
    for (int i = 0; i < 4; ++i)
        #pragma unroll
        for (int j = 0; j < 8; ++j) acc[i][j] = 0.f;
    for (int k4 = 0; k4 < 19; ++k4) {
        float4 av[4];
        #pragma unroll
        for (int i = 0; i < 4; ++i)
            av[i] = *(const float4*)&As[tm * 4 + i][k4 * 4];
        #pragma unroll
        for (int kk = 0; kk < 4; ++kk) {
            float4 b0 = *(const float4*)&Ws[k4 * 4 + kk][tn * 8];
            float4 b1 = *(const float4*)&Ws[k4 * 4 + kk][tn * 8 + 4];
            #pragma unroll
            for (int i = 0; i < 4; ++i) {
                float a = ((const float*)&av[i])[kk];
                acc[i][0] += a * b0.x; acc[i][1] += a * b0.y;
                acc[i][2] += a * b0.z; acc[i][3] += a * b0.w;
                acc[i][4] += a * b1.x; acc[i][5] += a * b1.y;
                acc[i][6] += a * b1.z; acc[i][7] += a * b1.w;
            }
        }
    }
    // epilogue: no bias, no relu; scale by nrm_src for next layer's gather
    #pragma unroll
    for (int i = 0; i < 4; ++i) {
        int n = m0 + tm * 4 + i;
        float ns = nrm[n];
        float4 o0 = make_float4(acc[i][0] * ns, acc[i][1] * ns, acc[i][2] * ns, acc[i][3] * ns);
        float4 o1 = make_float4(acc[i][4] * ns, acc[i][5] * ns, acc[i][6] * ns, acc[i][7] * ns);
        *(float4*)&hn[n * 128 + tn * 8] = o0;
        *(float4*)&hn[n * 128 + tn * 8 + 4] = o1;
    }
}

extern "C" void kernel_launch(void* const* d_in, const int* in_sizes, int n_in,
                              void* d_out, int out_size, void* d_ws, size_t ws_size,
                              hipStream_t stream) {
    const float* x  = (const float*)d_in[0];
    const int* src  = (const int*)d_in[1];
    const int* dst  = (const int*)d_in[2];
    const float* Wi = (const float*)d_in[3];
    const float* W1 = (const float*)d_in[4];
    const float* b1 = (const float*)d_in[5];
    const float* W2 = (const float*)d_in[6];
    const float* b2 = (const float*)d_in[7];
    const float* W3 = (const float*)d_in[8];
    const float* b3 = (const float*)d_in[9];

    char* ws = (char*)d_ws;
    int* deg_out   = (int*)(ws + OFF_DEG_OUT);
    int* deg_in    = (int*)(ws + OFF_DEG_IN);
    int* cursor    = (int*)(ws + OFF_CURSOR);
    int* counter   = (int*)(ws + OFF_COUNTER);
    int* row_start = (int*)(ws + OFF_ROWSTART);
    float* nrm_src = (float*)(ws + OFF_NRM_SRC);
    float* nrm_dst = (float*)(ws + OFF_NRM_DST);
    int* csr       = (int*)(ws + OFF_CSR);
    float* agg     = (float*)(ws + OFF_AGG);
    float* hn      = (float*)d_out;   // reuse output buffer (NN*128 fp32) as h scratch

    // zero deg_out, deg_in, cursor, counter in one contiguous memset
    hipMemsetAsync(ws, 0, OFF_COUNTER + 4, stream);
    k_count<<<NE / 256, 256, 0, stream>>>(src, dst, deg_out, deg_in);
    k_reserve<<<NN / 256, 256, 0, stream>>>(deg_in, deg_out, row_start, nrm_src, nrm_dst, counter);
    k_fill<<<NE / 256, 256, 0, stream>>>(src, dst, row_start, cursor, csr);
    k_gemm_init<<<NN / 64, 256, 0, stream>>>(x, Wi, nrm_src, hn);

    const float* Wl[3] = {W1, W2, W3};
    const float* bl[3] = {b1, b2, b3};
    for (int L = 0; L < 3; ++L) {
        k_agg<<<NN / 8, 256, 0, stream>>>((const float4*)hn, csr, row_start, deg_in,
                                          nrm_dst, (float4*)agg);
        int last = (L == 2);
        k_gemm128<<<NN / 64, 256, 0, stream>>>(agg, Wl[L], bl[L], nrm_src, hn, last);
    }
}

// Round 3
// 646.061 us; speedup vs baseline: 1.1708x; 1.1708x over previous
//
#include <hip/hip_runtime.h>

#define NN 131072   // total nodes (256 graphs x 512)
#define NE 1048576  // edges
// ws layout (bytes); total = 0x2709000 (~41 MB). hn (bf16) lives in d_out.
#define OFF_DEG_OUT   0x000000
#define OFF_DEG_IN    0x080000
#define OFF_CURSOR    0x100000
#define OFF_COUNTER   0x180000
#define OFF_ROWSTART  0x181000
#define OFF_NRM_SRC   0x201000
#define OFF_NRM_DST   0x281000
#define OFF_CSR       0x301000   // int [NE]  (4 MB)
#define OFF_WT        0x701000   // bf16 [128][128] transposed weights (32 KB)
#define OFF_AGG       0x709000   // bf16 [NN][128] (33.5 MB)

typedef __attribute__((ext_vector_type(8))) short bf16x8;
typedef __attribute__((ext_vector_type(4))) float f32x4;

static __device__ __forceinline__ float blo(unsigned u){ return __uint_as_float(u << 16); }
static __device__ __forceinline__ float bhi(unsigned u){ return __uint_as_float(u & 0xffff0000u); }
static __device__ __forceinline__ unsigned f2b(float f){
    unsigned u = __float_as_uint(f);
    return (u + 0x7fffu + ((u >> 16) & 1u)) >> 16;   // round-to-nearest-even
}
static __device__ __forceinline__ unsigned pack2(float a, float b){
    return f2b(a) | (f2b(b) << 16);
}

__global__ __launch_bounds__(256) void k_count(const int* __restrict__ src,
                                               const int* __restrict__ dst,
                                               int* __restrict__ deg_out,
                                               int* __restrict__ deg_in) {
    int e = blockIdx.x * 256 + threadIdx.x;
    atomicAdd(&deg_out[src[e]], 1);
    atomicAdd(&deg_in[dst[e]], 1);
}

__global__ __launch_bounds__(256) void k_reserve(const int* __restrict__ deg_in,
                                                 const int* __restrict__ deg_out,
                                                 int* __restrict__ row_start,
                                                 float* __restrict__ nrm_src,
                                                 float* __restrict__ nrm_dst,
                                                 int* __restrict__ counter) {
    int n = blockIdx.x * 256 + threadIdx.x;
    int lane = threadIdx.x & 63;
    int di = deg_in[n];
    int dq = deg_out[n];
    nrm_dst[n] = rsqrtf((float)(di > 1 ? di : 1));
    nrm_src[n] = rsqrtf((float)(dq > 1 ? dq : 1));
    int x = di;
    #pragma unroll
    for (int off = 1; off < 64; off <<= 1) {
        int v = __shfl_up(x, off, 64);
        if (lane >= off) x += v;
    }
    int base = 0;
    if (lane == 63) base = atomicAdd(counter, x);
    base = __shfl(base, 63, 64);
    row_start[n] = base + x - di;   // exclusive within wave
}

__global__ __launch_bounds__(256) void k_fill(const int* __restrict__ src,
                                              const int* __restrict__ dst,
                                              const int* __restrict__ row_start,
                                              int* __restrict__ cursor,
                                              int* __restrict__ csr) {
    int e = blockIdx.x * 256 + threadIdx.x;
    int d = dst[e];
    int pos = atomicAdd(&cursor[d], 1);
    csr[row_start[d] + pos] = src[e];
}

// transpose+convert W [k][n] fp32 -> Wt [n][k] bf16
__global__ __launch_bounds__(256) void k_wprep(const float* __restrict__ W,
                                               unsigned short* __restrict__ Wt) {
    int idx = blockIdx.x * 256 + threadIdx.x;   // 16384
    int k = idx >> 7, n = idx & 127;
    Wt[n * 128 + k] = (unsigned short)f2b(W[k * 128 + n]);
}

// aggregation over bf16 rows: 32 lanes/node, lane owns 4 bf16 cols (uint2); fp32 accum
__global__ __launch_bounds__(256) void k_agg(const uint2* __restrict__ hn,
                                             const int* __restrict__ csr,
                                             const int* __restrict__ row_start,
                                             const int* __restrict__ deg_in,
                                             const float* __restrict__ nrm_dst,
                                             uint2* __restrict__ agg) {
    int g = threadIdx.x >> 5;
    int lane = threadIdx.x & 31;
    int n = blockIdx.x * 8 + g;
    int rs = row_start[n];
    int cnt = deg_in[n];
    float a0 = 0.f, a1 = 0.f, a2 = 0.f, a3 = 0.f;
    for (int i = 0; i < cnt; ++i) {
        int s = csr[rs + i];
        uint2 v = hn[s * 32 + lane];
        a0 += blo(v.x); a1 += bhi(v.x);
        a2 += blo(v.y); a3 += bhi(v.y);
    }
    float nd = nrm_dst[n];
    uint2 o;
    o.x = pack2(a0 * nd, a1 * nd);
    o.y = pack2(a2 * nd, a3 * nd);
    agg[n * 32 + lane] = o;
}

// MFMA GEMM: Out[m][n] = relu(A[m][:] @ W + b) (*nrm unless last)
// A bf16 [NN][128]; Wt bf16 [n][k]; 256 thr = 4 waves; wave tile 16x128; block 64 rows.
// A-frag: lane holds A[m=lane&15][k=quad*8+j]; B-frag: B[k=quad*8+j][n=lane&15];
// C/D:    lane reg r -> row quad*4+r, col lane&15.
__global__ __launch_bounds__(256) void k_gemm_mfma(const unsigned short* __restrict__ A,
                                                   const unsigned short* __restrict__ Wt,
                                                   const float* __restrict__ bias,
                                                   const float* __restrict__ nrm,
                                                   void* __restrict__ OutP, int last) {
    __shared__ unsigned int lds[128 * 68];   // Wt rows, stride 68 words; reused for epilogue tile [64][132]
    __shared__ float bias_s[128];
    int tid = threadIdx.x;
    int wave = tid >> 6, lane = tid & 63;
    int quad = lane >> 4, l16 = lane & 15;
    int m0 = blockIdx.x * 64;

    {   // stage Wt: thread copies 128 B of row n (two threads per 256 B row)
        int n = tid >> 1, h = tid & 1;
        const uint4* s4 = (const uint4*)(Wt + n * 128 + h * 64);
        unsigned int* d = &lds[n * 68 + h * 32];
        #pragma unroll
        for (int j = 0; j < 8; ++j) *(uint4*)(d + j * 4) = s4[j];
    }
    if (tid < 128) bias_s[tid] = bias[tid];
    __syncthreads();

    f32x4 acc[8];
    #pragma unroll
    for (int t = 0; t < 8; ++t) acc[t] = (f32x4){0.f, 0.f, 0.f, 0.f};

    const unsigned short* arow = A + (size_t)(m0 + wave * 16 + l16) * 128 + quad * 8;
    #pragma unroll
    for (int kt = 0; kt < 128; kt += 32) {
        bf16x8 af = *(const bf16x8*)(arow + kt);
        #pragma unroll
        for (int t = 0; t < 8; ++t) {
            bf16x8 bf = *(const bf16x8*)&lds[(t * 16 + l16) * 68 + (kt >> 1) + quad * 4];
            acc[t] = __builtin_amdgcn_mfma_f32_16x16x32_bf16(af, bf, acc[t], 0, 0, 0);
        }
    }
    __syncthreads();           // everyone done reading Wt; reuse LDS for epilogue
    float* at = (float*)lds;   // [64][132]
    #pragma unroll
    for (int t = 0; t < 8; ++t)
        #pragma unroll
        for (int r = 0; r < 4; ++r)
            at[(wave * 16 + quad * 4 + r) * 132 + t * 16 + l16] = acc[t][r];
    __syncthreads();

    int r = tid >> 2, c0 = (tid & 3) * 32;   // row within tile, 32-col slice
    int m = m0 + r;
    if (!last) {
        float ns = nrm[m];
        unsigned short* Out = (unsigned short*)OutP;
        unsigned q[16] __attribute__((aligned(16)));
        #pragma unroll
        for (int j = 0; j < 16; ++j) {
            float v0 = at[r * 132 + c0 + 2 * j]     + bias_s[c0 + 2 * j];
            float v1 = at[r * 132 + c0 + 2 * j + 1] + bias_s[c0 + 2 * j + 1];
            v0 = (v0 > 0.f ? v0 : 0.f) * ns;
            v1 = (v1 > 0.f ? v1 : 0.f) * ns;
            q[j] = pack2(v0, v1);
        }
        #pragma unroll
        for (int j = 0; j < 4; ++j)
            *(uint4*)(Out + (size_t)m * 128 + c0 + j * 8) = *(const uint4*)&q[j * 4];
    } else {
        float* Out = (float*)OutP;
        #pragma unroll
        for (int j = 0; j < 8; ++j) {
            float4 v;
            v.x = at[r * 132 + c0 + j * 4 + 0] + bias_s[c0 + j * 4 + 0];
            v.y = at[r * 132 + c0 + j * 4 + 1] + bias_s[c0 + j * 4 + 1];
            v.z = at[r * 132 + c0 + j * 4 + 2] + bias_s[c0 + j * 4 + 2];
            v.w = at[r * 132 + c0 + j * 4 + 3] + bias_s[c0 + j * 4 + 3];
            v.x = v.x > 0.f ? v.x : 0.f;
            v.y = v.y > 0.f ? v.y : 0.f;
            v.z = v.z > 0.f ? v.z : 0.f;
            v.w = v.w > 0.f ? v.w : 0.f;
            *(float4*)&Out[(size_t)m * 128 + c0 + j * 4] = v;
        }
    }
}

// hn0 = (x @ W_init) * nrm_src -> bf16; x: [NN][74] fp32, W: [74][128] fp32
__global__ __launch_bounds__(256) void k_gemm_init(const float* __restrict__ X,
                                                   const float* __restrict__ W,
                                                   const float* __restrict__ nrm,
                                                   unsigned short* __restrict__ hn) {
    __shared__ float As[64][80];
    __shared__ float Ws[76][132];
    int tid = threadIdx.x;
    int m0 = blockIdx.x * 64;
    int tm = tid >> 4, tn = tid & 15;
    for (int idx = tid; idx < 2368; idx += 256) {   // 64 x 74 fp32 as float2
        int m = idx / 37, t = idx - m * 37;
        float2 v = *(const float2*)&X[(m0 + m) * 74 + t * 2];
        As[m][t * 2]     = v.x;
        As[m][t * 2 + 1] = v.y;
    }
    for (int idx = tid; idx < 64 * 6; idx += 256) {   // zero K-pad cols 74..79
        int m = idx / 6, c = 74 + idx % 6;
        As[m][c] = 0.f;
    }
    for (int idx = tid; idx < 2368; idx += 256) {   // W: 74 x 128 fp32 as float4
        int kk = idx >> 5, j4 = idx & 31;
        float4 v = *(const float4*)&W[kk * 128 + j4 * 4];
        *(float4*)&Ws[kk][j4 * 4] = v;
    }
    {   // zero W pad rows 74,75
        int kk = 74 + (tid >> 7), j = tid & 127;
        Ws[kk][j] = 0.f;
    }
    __syncthreads();
    float acc[4][8];
    #pragma unroll
    for (int i = 0; i < 4; ++i)
        #pragma unroll
        for (int j = 0; j < 8; ++j) acc[i][j] = 0.f;
    for (int k4 = 0; k4 < 19; ++k4) {
        float4 av[4];
        #pragma unroll
        for (int i = 0; i < 4; ++i)
            av[i] = *(const float4*)&As[tm * 4 + i][k4 * 4];
        #pragma unroll
        for (int kk = 0; kk < 4; ++kk) {
            float4 b0 = *(const float4*)&Ws[k4 * 4 + kk][tn * 8];
            float4 b1 = *(const float4*)&Ws[k4 * 4 + kk][tn * 8 + 4];
            #pragma unroll
            for (int i = 0; i < 4; ++i) {
                float a = ((const float*)&av[i])[kk];
                acc[i][0] += a * b0.x; acc[i][1] += a * b0.y;
                acc[i][2] += a * b0.z; acc[i][3] += a * b0.w;
                acc[i][4] += a * b1.x; acc[i][5] += a * b1.y;
                acc[i][6] += a * b1.z; acc[i][7] += a * b1.w;
            }
        }
    }
    #pragma unroll
    for (int i = 0; i < 4; ++i) {
        int n = m0 + tm * 4 + i;
        float ns = nrm[n];
        uint4 o;
        o.x = pack2(acc[i][0] * ns, acc[i][1] * ns);
        o.y = pack2(acc[i][2] * ns, acc[i][3] * ns);
        o.z = pack2(acc[i][4] * ns, acc[i][5] * ns);
        o.w = pack2(acc[i][6] * ns, acc[i][7] * ns);
        *(uint4*)&hn[n * 128 + tn * 8] = o;
    }
}

extern "C" void kernel_launch(void* const* d_in, const int* in_sizes, int n_in,
                              void* d_out, int out_size, void* d_ws, size_t ws_size,
                              hipStream_t stream) {
    const float* x  = (const float*)d_in[0];
    const int* src  = (const int*)d_in[1];
    const int* dst  = (const int*)d_in[2];
    const float* Wi = (const float*)d_in[3];
    const float* W1 = (const float*)d_in[4];
    const float* b1 = (const float*)d_in[5];
    const float* W2 = (const float*)d_in[6];
    const float* b2 = (const float*)d_in[7];
    const float* W3 = (const float*)d_in[8];
    const float* b3 = (const float*)d_in[9];

    char* ws = (char*)d_ws;
    int* deg_out   = (int*)(ws + OFF_DEG_OUT);
    int* deg_in    = (int*)(ws + OFF_DEG_IN);
    int* cursor    = (int*)(ws + OFF_CURSOR);
    int* counter   = (int*)(ws + OFF_COUNTER);
    int* row_start = (int*)(ws + OFF_ROWSTART);
    float* nrm_src = (float*)(ws + OFF_NRM_SRC);
    float* nrm_dst = (float*)(ws + OFF_NRM_DST);
    int* csr       = (int*)(ws + OFF_CSR);
    unsigned short* Wt  = (unsigned short*)(ws + OFF_WT);
    unsigned short* agg = (unsigned short*)(ws + OFF_AGG);
    unsigned short* hn  = (unsigned short*)d_out;   // bf16 h scratch in d_out (dead before final write)

    hipMemsetAsync(ws, 0, OFF_COUNTER + 4, stream);
    k_count<<<NE / 256, 256, 0, stream>>>(src, dst, deg_out, deg_in);
    k_reserve<<<NN / 256, 256, 0, stream>>>(deg_in, deg_out, row_start, nrm_src, nrm_dst, counter);
    k_fill<<<NE / 256, 256, 0, stream>>>(src, dst, row_start, cursor, csr);
    k_gemm_init<<<NN / 64, 256, 0, stream>>>(x, Wi, nrm_src, hn);

    const float* Wl[3] = {W1, W2, W3};
    const float* bl[3] = {b1, b2, b3};
    for (int L = 0; L < 3; ++L) {
        int last = (L == 2);
        k_wprep<<<64, 256, 0, stream>>>(Wl[L], Wt);
        k_agg<<<NN / 8, 256, 0, stream>>>((const uint2*)hn, csr, row_start, deg_in,
                                          nrm_dst, (uint2*)agg);
        k_gemm_mfma<<<NN / 64, 256, 0, stream>>>(agg, Wt, bl[L], nrm_src,
                                                 last ? (void*)d_out : (void*)hn, last);
    }
}

// Round 4
// 538.918 us; speedup vs baseline: 1.4036x; 1.1988x over previous
//
#include <hip/hip_runtime.h>

#define NN 131072   // total nodes (256 graphs x 512)
#define NE 1048576  // edges
// ws layout (bytes); total = 0x4300000 (~70 MB)
#define OFF_DEG_OUT 0x000000   // int[NN]
#define OFF_CURSOR  0x080000   // int[NN] -> becomes deg_in
#define OFF_NRM_SRC 0x100000   // f32[NN]
#define OFF_NRM_DST 0x180000   // f32[NN]
#define OFF_WT      0x200000   // bf16 3x[128][128] transposed layer weights (96 KB)
#define OFF_WTI     0x218000   // bf16 [128][96] transposed init weight, K-padded (24 KB)
#define OFF_BUCKET  0x300000   // int[NN][64] adjacency buckets (33.5 MB)
#define OFF_HN      0x2300000  // bf16[NN][128] (33.5 MB)

typedef __attribute__((ext_vector_type(8))) short bf16x8;
typedef __attribute__((ext_vector_type(4))) float f32x4;

static __device__ __forceinline__ float blo(unsigned u){ return __uint_as_float(u << 16); }
static __device__ __forceinline__ float bhi(unsigned u){ return __uint_as_float(u & 0xffff0000u); }
static __device__ __forceinline__ unsigned f2b(float f){
    unsigned u = __float_as_uint(f);
    return (u + 0x7fffu + ((u >> 16) & 1u)) >> 16;   // round-to-nearest-even
}
static __device__ __forceinline__ unsigned pack2(float a, float b){
    return f2b(a) | (f2b(b) << 16);
}

// one pass: deg_out count + bucketed CSR build (cursor ends as deg_in)
__global__ __launch_bounds__(256) void k_fill(const int* __restrict__ src,
                                              const int* __restrict__ dst,
                                              int* __restrict__ deg_out,
                                              int* __restrict__ cursor,
                                              int* __restrict__ bucket) {
    int e = blockIdx.x * 256 + threadIdx.x;
    int s = src[e], d = dst[e];
    atomicAdd(&deg_out[s], 1);
    int pos = atomicAdd(&cursor[d], 1);
    if (pos < 64) bucket[(size_t)d * 64 + pos] = s;   // deg>=64 has P~1e-40
}

__global__ __launch_bounds__(256) void k_nrm(const int* __restrict__ deg_out,
                                             const int* __restrict__ deg_in,
                                             float* __restrict__ nrm_src,
                                             float* __restrict__ nrm_dst) {
    int n = blockIdx.x * 256 + threadIdx.x;
    int dq = deg_out[n], di = deg_in[n];
    nrm_src[n] = rsqrtf((float)(dq > 1 ? dq : 1));
    nrm_dst[n] = rsqrtf((float)(di > 1 ? di : 1));
}

// all weight transposes in one launch: Wt[L][n][k] (layers) + Wti[n][k0..95] (init, K-padded)
__global__ __launch_bounds__(256) void k_wprep(const float* __restrict__ W1,
                                               const float* __restrict__ W2,
                                               const float* __restrict__ W3,
                                               const float* __restrict__ Wi,
                                               unsigned short* __restrict__ Wt,
                                               unsigned short* __restrict__ Wti) {
    int idx = blockIdx.x * 256 + threadIdx.x;
    if (idx < 49152) {
        int L = idx >> 14, rem = idx & 16383;
        int k = rem >> 7, n = rem & 127;
        const float* W = L == 0 ? W1 : (L == 1 ? W2 : W3);
        Wt[L * 16384 + n * 128 + k] = (unsigned short)f2b(W[k * 128 + n]);
    } else if (idx < 61440) {
        int rem = idx - 49152;
        int n = rem / 96, k = rem - n * 96;
        float v = (k < 74) ? Wi[k * 128 + n] : 0.f;
        Wti[n * 96 + k] = (unsigned short)f2b(v);
    }
}

// hn0 = bf16((x @ W_init) * nrm_src) via MFMA; X fp32 [NN][74] quantized during staging, K->96
__global__ __launch_bounds__(256) void k_init(const float* __restrict__ X,
                                              const unsigned short* __restrict__ Wti,
                                              const float* __restrict__ nrm,
                                              unsigned short* __restrict__ hn) {
    __shared__ unsigned int sbuf[9984];        // 39.9 KB
    unsigned int* xs  = sbuf;                  // [64][52] words (96 bf16 + pad)
    unsigned int* wsb = sbuf + 3328;           // [128][52] words
    float* ep = (float*)sbuf;                  // [64][132] fp32 epilogue reuse (8448 words)
    int tid = threadIdx.x;
    int m0 = blockIdx.x * 64;

    for (int idx = tid; idx < 2368; idx += 256) {        // X: 64 rows x 37 float2, quantize
        int m = idx / 37, t = idx - m * 37;
        float2 v = *(const float2*)&X[(size_t)(m0 + m) * 74 + t * 2];
        xs[m * 52 + t] = pack2(v.x, v.y);
    }
    {   // zero pad words 37..51 of each xs row
        int m = tid >> 4, c = tid & 15;
        if (c < 15) { xs[m * 52 + 37 + c] = 0u; xs[(m + 16) * 52 + 37 + c] = 0u;
                      xs[(m + 32) * 52 + 37 + c] = 0u; xs[(m + 48) * 52 + 37 + c] = 0u; }
    }
    {   // stage Wti: 128 rows x 48 words, 2 threads/row x 6 uint4
        int n = tid >> 1, h = tid & 1;
        const uint4* s4 = (const uint4*)(Wti + n * 96 + h * 48);
        #pragma unroll
        for (int j = 0; j < 6; ++j)
            *(uint4*)&wsb[n * 52 + h * 24 + j * 4] = s4[j];
    }
    __syncthreads();

    f32x4 acc[8];
    #pragma unroll
    for (int t = 0; t < 8; ++t) acc[t] = (f32x4){0.f, 0.f, 0.f, 0.f};
    int wave = tid >> 6, lane = tid & 63, quad = lane >> 4, l16 = lane & 15;
    int arow = (wave * 16 + l16) * 52 + quad * 4;
    #pragma unroll
    for (int ks = 0; ks < 3; ++ks) {
        bf16x8 af = *(const bf16x8*)&xs[arow + ks * 16];
        #pragma unroll
        for (int t = 0; t < 8; ++t) {
            bf16x8 bf = *(const bf16x8*)&wsb[(t * 16 + l16) * 52 + ks * 16 + quad * 4];
            acc[t] = __builtin_amdgcn_mfma_f32_16x16x32_bf16(af, bf, acc[t], 0, 0, 0);
        }
    }
    __syncthreads();
    #pragma unroll
    for (int t = 0; t < 8; ++t)
        #pragma unroll
        for (int r = 0; r < 4; ++r)
            ep[(wave * 16 + quad * 4 + r) * 132 + t * 16 + l16] = acc[t][r];
    __syncthreads();
    int r = tid >> 2, c0 = (tid & 3) * 32;
    int m = m0 + r;
    float ns = nrm[m];
    unsigned q[16] __attribute__((aligned(16)));
    #pragma unroll
    for (int j = 0; j < 16; ++j)
        q[j] = pack2(ep[r * 132 + c0 + 2 * j] * ns, ep[r * 132 + c0 + 2 * j + 1] * ns);
    #pragma unroll
    for (int j = 0; j < 4; ++j)
        *(uint4*)(hn + (size_t)m * 128 + c0 + j * 8) = *(const uint4*)&q[j * 4];
}

// fused layer: gather+normalize into LDS bf16 A-tile, MFMA vs Wt, fused epilogue
__global__ __launch_bounds__(256) void k_layer(const uint4* __restrict__ hn4,
                                               const int* __restrict__ bucket,
                                               const int* __restrict__ deg_in,
                                               const float* __restrict__ nrm_dst,
                                               const float* __restrict__ nrm_src,
                                               const unsigned short* __restrict__ Wt,
                                               const float* __restrict__ bias,
                                               void* __restrict__ OutP, int last) {
    __shared__ unsigned int sbuf[13184];   // 52.7 KB
    unsigned int* wt = sbuf;               // [128][68] words
    unsigned int* at = sbuf + 8704;        // [64][68] words (bf16 A-tile)
    float* bias_s = (float*)(sbuf + 13056);
    float* ep = (float*)sbuf;              // [64][132] fp32 epilogue reuse
    int tid = threadIdx.x;
    int m0 = blockIdx.x * 64;

    {   // stage Wt: 2 threads per 256 B row
        int n = tid >> 1, h = tid & 1;
        const uint4* s4 = (const uint4*)(Wt + n * 128 + h * 64);
        unsigned int* d = &wt[n * 68 + h * 32];
        #pragma unroll
        for (int j = 0; j < 8; ++j) *(uint4*)(d + j * 4) = s4[j];
    }
    if (tid < 128) bias_s[tid] = bias[tid];

    // phase 1: gather 64 node rows; 16 lanes/node (uint4 = 16 B each), 4 passes
    int g = tid >> 4, l16p = tid & 15;
    #pragma unroll
    for (int pass = 0; pass < 4; ++pass) {
        int nl = pass * 16 + g;
        int n = m0 + nl;
        int cnt = deg_in[n];
        const int* brow = bucket + (size_t)n * 64;
        float a0 = 0, a1 = 0, a2 = 0, a3 = 0, a4 = 0, a5 = 0, a6 = 0, a7 = 0;
        for (int c = 0; c < cnt; c += 4) {
            int4 s4 = *(const int4*)&brow[c];
            int lim = cnt - c;
            {            uint4 v = hn4[(size_t)s4.x * 16 + l16p];
                a0 += blo(v.x); a1 += bhi(v.x); a2 += blo(v.y); a3 += bhi(v.y);
                a4 += blo(v.z); a5 += bhi(v.z); a6 += blo(v.w); a7 += bhi(v.w); }
            if (lim > 1) { uint4 v = hn4[(size_t)s4.y * 16 + l16p];
                a0 += blo(v.x); a1 += bhi(v.x); a2 += blo(v.y); a3 += bhi(v.y);
                a4 += blo(v.z); a5 += bhi(v.z); a6 += blo(v.w); a7 += bhi(v.w); }
            if (lim > 2) { uint4 v = hn4[(size_t)s4.z * 16 + l16p];
                a0 += blo(v.x); a1 += bhi(v.x); a2 += blo(v.y); a3 += bhi(v.y);
                a4 += blo(v.z); a5 += bhi(v.z); a6 += blo(v.w); a7 += bhi(v.w); }
            if (lim > 3) { uint4 v = hn4[(size_t)s4.w * 16 + l16p];
                a0 += blo(v.x); a1 += bhi(v.x); a2 += blo(v.y); a3 += bhi(v.y);
                a4 += blo(v.z); a5 += bhi(v.z); a6 += blo(v.w); a7 += bhi(v.w); }
        }
        float nd = nrm_dst[n];
        uint4 o;
        o.x = pack2(a0 * nd, a1 * nd); o.y = pack2(a2 * nd, a3 * nd);
        o.z = pack2(a4 * nd, a5 * nd); o.w = pack2(a6 * nd, a7 * nd);
        *(uint4*)&at[nl * 68 + l16p * 4] = o;
    }
    __syncthreads();

    // phase 2: MFMA 64x128 = A(64x128) @ Wt^T
    f32x4 acc[8];
    #pragma unroll
    for (int t = 0; t < 8; ++t) acc[t] = (f32x4){0.f, 0.f, 0.f, 0.f};
    int wave = tid >> 6, lane = tid & 63, quad = lane >> 4, l16 = lane & 15;
    int arow = (wave * 16 + l16) * 68 + quad * 4;
    #pragma unroll
    for (int ks = 0; ks < 4; ++ks) {
        bf16x8 af = *(const bf16x8*)&at[arow + ks * 16];
        #pragma unroll
        for (int t = 0; t < 8; ++t) {
            bf16x8 bf = *(const bf16x8*)&wt[(t * 16 + l16) * 68 + ks * 16 + quad * 4];
            acc[t] = __builtin_amdgcn_mfma_f32_16x16x32_bf16(af, bf, acc[t], 0, 0, 0);
        }
    }
    __syncthreads();
    #pragma unroll
    for (int t = 0; t < 8; ++t)
        #pragma unroll
        for (int r = 0; r < 4; ++r)
            ep[(wave * 16 + quad * 4 + r) * 132 + t * 16 + l16] = acc[t][r];
    __syncthreads();

    int r = tid >> 2, c0 = (tid & 3) * 32;
    int m = m0 + r;
    if (!last) {
        float ns = nrm_src[m];
        unsigned short* Out = (unsigned short*)OutP;
        unsigned q[16] __attribute__((aligned(16)));
        #pragma unroll
        for (int j = 0; j < 16; ++j) {
            float v0 = ep[r * 132 + c0 + 2 * j]     + bias_s[c0 + 2 * j];
            float v1 = ep[r * 132 + c0 + 2 * j + 1] + bias_s[c0 + 2 * j + 1];
            v0 = (v0 > 0.f ? v0 : 0.f) * ns;
            v1 = (v1 > 0.f ? v1 : 0.f) * ns;
            q[j] = pack2(v0, v1);
        }
        #pragma unroll
        for (int j = 0; j < 4; ++j)
            *(uint4*)(Out + (size_t)m * 128 + c0 + j * 8) = *(const uint4*)&q[j * 4];
    } else {
        float* Out = (float*)OutP;
        #pragma unroll
        for (int j = 0; j < 8; ++j) {
            float4 v;
            v.x = ep[r * 132 + c0 + j * 4 + 0] + bias_s[c0 + j * 4 + 0];
            v.y = ep[r * 132 + c0 + j * 4 + 1] + bias_s[c0 + j * 4 + 1];
            v.z = ep[r * 132 + c0 + j * 4 + 2] + bias_s[c0 + j * 4 + 2];
            v.w = ep[r * 132 + c0 + j * 4 + 3] + bias_s[c0 + j * 4 + 3];
            v.x = v.x > 0.f ? v.x : 0.f;
            v.y = v.y > 0.f ? v.y : 0.f;
            v.z = v.z > 0.f ? v.z : 0.f;
            v.w = v.w > 0.f ? v.w : 0.f;
            *(float4*)&Out[(size_t)m * 128 + c0 + j * 4] = v;
        }
    }
}

extern "C" void kernel_launch(void* const* d_in, const int* in_sizes, int n_in,
                              void* d_out, int out_size, void* d_ws, size_t ws_size,
                              hipStream_t stream) {
    const float* x  = (const float*)d_in[0];
    const int* src  = (const int*)d_in[1];
    const int* dst  = (const int*)d_in[2];
    const float* Wi = (const float*)d_in[3];
    const float* W1 = (const float*)d_in[4];
    const float* b1 = (const float*)d_in[5];
    const float* W2 = (const float*)d_in[6];
    const float* b2 = (const float*)d_in[7];
    const float* W3 = (const float*)d_in[8];
    const float* b3 = (const float*)d_in[9];

    char* ws = (char*)d_ws;
    int* deg_out   = (int*)(ws + OFF_DEG_OUT);
    int* cursor    = (int*)(ws + OFF_CURSOR);   // becomes deg_in
    float* nrm_src = (float*)(ws + OFF_NRM_SRC);
    float* nrm_dst = (float*)(ws + OFF_NRM_DST);
    unsigned short* Wt  = (unsigned short*)(ws + OFF_WT);
    unsigned short* Wti = (unsigned short*)(ws + OFF_WTI);
    int* bucket    = (int*)(ws + OFF_BUCKET);
    unsigned short* hnA = (unsigned short*)(ws + OFF_HN);
    unsigned short* hnB = (unsigned short*)d_out;   // bf16 ping buffer inside d_out

    hipMemsetAsync(ws, 0, 0x100000, stream);        // zero deg_out + cursor
    k_fill<<<NE / 256, 256, 0, stream>>>(src, dst, deg_out, cursor, bucket);
    k_nrm<<<NN / 256, 256, 0, stream>>>(deg_out, cursor, nrm_src, nrm_dst);
    k_wprep<<<240, 256, 0, stream>>>(W1, W2, W3, Wi, Wt, Wti);
    k_init<<<NN / 64, 256, 0, stream>>>(x, Wti, nrm_src, hnA);

    const float* bl[3] = {b1, b2, b3};
    // ping-pong: L0 hnA->hnB(bf16), L1 hnB->hnA, L2 hnA->d_out(fp32)
    k_layer<<<NN / 64, 256, 0, stream>>>((const uint4*)hnA, bucket, cursor, nrm_dst,
                                         nrm_src, Wt,          bl[0], (void*)hnB, 0);
    k_layer<<<NN / 64, 256, 0, stream>>>((const uint4*)hnB, bucket, cursor, nrm_dst,
                                         nrm_src, Wt + 16384,  bl[1], (void*)hnA, 0);
    k_layer<<<NN / 64, 256, 0, stream>>>((const uint4*)hnA, bucket, cursor, nrm_dst,
                                         nrm_src, Wt + 32768,  bl[2], d_out, 1);
}

// Round 5
// 508.873 us; speedup vs baseline: 1.4864x; 1.0590x over previous
//
#include <hip/hip_runtime.h>

#define NN 131072   // total nodes (256 graphs x 512)
#define NE 1048576  // edges
// ws layout (bytes); total = 0x4200000 (~69 MB)
#define OFF_DEG_OUT 0x000000   // int[NN]
#define OFF_CURSOR  0x080000   // int[NN] -> becomes deg_in
#define OFF_WT      0x100000   // bf16 3x[128][128] transposed layer weights (96 KB)
#define OFF_WTI     0x118000   // bf16 [128][96] transposed init weight, K-padded (24 KB)
#define OFF_BUCKET  0x200000   // int[NN][64] adjacency buckets (33.5 MB)
#define OFF_HN      0x2200000  // bf16[NN][128] (33.5 MB)

typedef __attribute__((ext_vector_type(8))) short bf16x8;
typedef __attribute__((ext_vector_type(4))) float f32x4;

static __device__ __forceinline__ float blo(unsigned u){ return __uint_as_float(u << 16); }
static __device__ __forceinline__ float bhi(unsigned u){ return __uint_as_float(u & 0xffff0000u); }
static __device__ __forceinline__ unsigned f2b(float f){
    unsigned u = __float_as_uint(f);
    return (u + 0x7fffu + ((u >> 16) & 1u)) >> 16;   // round-to-nearest-even
}
static __device__ __forceinline__ unsigned pack2(float a, float b){
    return f2b(a) | (f2b(b) << 16);
}

// one pass: deg_out count + bucketed CSR build (cursor ends as deg_in)
__global__ __launch_bounds__(256) void k_fill(const int* __restrict__ src,
                                              const int* __restrict__ dst,
                                              int* __restrict__ deg_out,
                                              int* __restrict__ cursor,
                                              int* __restrict__ bucket) {
    int e = blockIdx.x * 256 + threadIdx.x;
    int s = src[e], d = dst[e];
    atomicAdd(&deg_out[s], 1);
    int pos = atomicAdd(&cursor[d], 1);
    if (pos < 64) bucket[(size_t)d * 64 + pos] = s;   // deg>=64 has P~1e-40
}

// all weight transposes in one launch: Wt[L][n][k] (layers) + Wti[n][k0..95] (init, K-padded)
__global__ __launch_bounds__(256) void k_wprep(const float* __restrict__ W1,
                                               const float* __restrict__ W2,
                                               const float* __restrict__ W3,
                                               const float* __restrict__ Wi,
                                               unsigned short* __restrict__ Wt,
                                               unsigned short* __restrict__ Wti) {
    int idx = blockIdx.x * 256 + threadIdx.x;
    if (idx < 49152) {
        int L = idx >> 14, rem = idx & 16383;
        int k = rem >> 7, n = rem & 127;
        const float* W = L == 0 ? W1 : (L == 1 ? W2 : W3);
        Wt[L * 16384 + n * 128 + k] = (unsigned short)f2b(W[k * 128 + n]);
    } else if (idx < 61440) {
        int rem = idx - 49152;
        int n = rem / 96, k = rem - n * 96;
        float v = (k < 74) ? Wi[k * 128 + n] : 0.f;
        Wti[n * 96 + k] = (unsigned short)f2b(v);
    }
}

// hn0 = bf16((x @ W_init) * deg_out^-1/2) via MFMA; X staged+quantized in LDS, K->96
__global__ __launch_bounds__(256) void k_init(const float* __restrict__ X,
                                              const unsigned short* __restrict__ Wti,
                                              const int* __restrict__ deg_out,
                                              unsigned short* __restrict__ hn) {
    __shared__ unsigned int xs[64 * 52];   // 13.3 KB: 64 rows x 96 bf16 (+pad)
    int tid = threadIdx.x;
    int m0 = blockIdx.x * 64;

    for (int idx = tid; idx < 2368; idx += 256) {        // X: 64 rows x 37 float2, quantize
        int m = idx / 37, t = idx - m * 37;
        float2 v = *(const float2*)&X[(size_t)(m0 + m) * 74 + t * 2];
        xs[m * 52 + t] = pack2(v.x, v.y);
    }
    for (int idx = tid; idx < 64 * 15; idx += 256) {     // zero pad words 37..51
        int m = idx / 15, c = 37 + idx % 15;
        xs[m * 52 + c] = 0u;
    }
    __syncthreads();

    int wave = tid >> 6, lane = tid & 63, quad = lane >> 4, l16 = lane & 15;
    f32x4 acc[8];
    #pragma unroll
    for (int t = 0; t < 8; ++t) acc[t] = (f32x4){0.f, 0.f, 0.f, 0.f};
    int arow = (wave * 16 + l16) * 52 + quad * 4;
    #pragma unroll
    for (int ks = 0; ks < 3; ++ks) {
        bf16x8 af = *(const bf16x8*)&xs[arow + ks * 16];
        #pragma unroll
        for (int t = 0; t < 8; ++t) {
            bf16x8 bf = *(const bf16x8*)(Wti + (t * 16 + l16) * 96 + ks * 32 + quad * 8);
            acc[t] = __builtin_amdgcn_mfma_f32_16x16x32_bf16(af, bf, acc[t], 0, 0, 0);
        }
    }
    // direct epilogue from C-layout: row = quad*4+r, col = t*16+l16
    int mb = m0 + wave * 16 + quad * 4;
    float nsr[4];
    #pragma unroll
    for (int r = 0; r < 4; ++r) {
        int dq = deg_out[mb + r];
        nsr[r] = rsqrtf((float)(dq > 1 ? dq : 1));
    }
    #pragma unroll
    for (int t = 0; t < 8; ++t)
        #pragma unroll
        for (int r = 0; r < 4; ++r)
            hn[(size_t)(mb + r) * 128 + t * 16 + l16] = (unsigned short)f2b(acc[t][r] * nsr[r]);
}

// fused layer: gather+normalize into LDS bf16 A-tile, MFMA vs global Wt, direct epilogue
__global__ __launch_bounds__(256) void k_layer(const uint4* __restrict__ hn4,
                                               const int* __restrict__ bucket,
                                               const int* __restrict__ deg_in,
                                               const int* __restrict__ deg_out,
                                               const unsigned short* __restrict__ Wt,
                                               const float* __restrict__ bias,
                                               void* __restrict__ OutP, int last) {
    __shared__ unsigned int at[64 * 68];   // 17.4 KB bf16 A-tile, row stride 68 words
    int tid = threadIdx.x;
    int m0 = blockIdx.x * 64;

    // phase 1: gather 64 node rows; 16 lanes/node (uint4 = 16 B each), 4 passes
    int g = tid >> 4, l16p = tid & 15;
    #pragma unroll
    for (int pass = 0; pass < 4; ++pass) {
        int nl = pass * 16 + g;
        int n = m0 + nl;
        int cnt = deg_in[n];
        const int* brow = bucket + (size_t)n * 64;
        float a0 = 0, a1 = 0, a2 = 0, a3 = 0, a4 = 0, a5 = 0, a6 = 0, a7 = 0;
        for (int c = 0; c < cnt; c += 4) {
            int4 s4 = *(const int4*)&brow[c];
            int lim = cnt - c;
            {            uint4 v = hn4[(size_t)s4.x * 16 + l16p];
                a0 += blo(v.x); a1 += bhi(v.x); a2 += blo(v.y); a3 += bhi(v.y);
                a4 += blo(v.z); a5 += bhi(v.z); a6 += blo(v.w); a7 += bhi(v.w); }
            if (lim > 1) { uint4 v = hn4[(size_t)s4.y * 16 + l16p];
                a0 += blo(v.x); a1 += bhi(v.x); a2 += blo(v.y); a3 += bhi(v.y);
                a4 += blo(v.z); a5 += bhi(v.z); a6 += blo(v.w); a7 += bhi(v.w); }
            if (lim > 2) { uint4 v = hn4[(size_t)s4.z * 16 + l16p];
                a0 += blo(v.x); a1 += bhi(v.x); a2 += blo(v.y); a3 += bhi(v.y);
                a4 += blo(v.z); a5 += bhi(v.z); a6 += blo(v.w); a7 += bhi(v.w); }
            if (lim > 3) { uint4 v = hn4[(size_t)s4.w * 16 + l16p];
                a0 += blo(v.x); a1 += bhi(v.x); a2 += blo(v.y); a3 += bhi(v.y);
                a4 += blo(v.z); a5 += bhi(v.z); a6 += blo(v.w); a7 += bhi(v.w); }
        }
        float nd = rsqrtf((float)(cnt > 1 ? cnt : 1));
        uint4 o;
        o.x = pack2(a0 * nd, a1 * nd); o.y = pack2(a2 * nd, a3 * nd);
        o.z = pack2(a4 * nd, a5 * nd); o.w = pack2(a6 * nd, a7 * nd);
        *(uint4*)&at[nl * 68 + l16p * 4] = o;
    }
    __syncthreads();

    // phase 2: MFMA 64x128; B-frags straight from global Wt (L2-hot, 32 KB)
    f32x4 acc[8];
    #pragma unroll
    for (int t = 0; t < 8; ++t) acc[t] = (f32x4){0.f, 0.f, 0.f, 0.f};
    int wave = tid >> 6, lane = tid & 63, quad = lane >> 4, l16 = lane & 15;
    int arow = (wave * 16 + l16) * 68 + quad * 4;
    #pragma unroll
    for (int ks = 0; ks < 4; ++ks) {
        bf16x8 af = *(const bf16x8*)&at[arow + ks * 16];
        #pragma unroll
        for (int t = 0; t < 8; ++t) {
            bf16x8 bf = *(const bf16x8*)(Wt + (t * 16 + l16) * 128 + ks * 32 + quad * 8);
            acc[t] = __builtin_amdgcn_mfma_f32_16x16x32_bf16(af, bf, acc[t], 0, 0, 0);
        }
    }

    // direct epilogue from C-layout: row = quad*4+r, col = t*16+l16
    int mb = m0 + wave * 16 + quad * 4;
    if (!last) {
        float nsr[4];
        #pragma unroll
        for (int r = 0; r < 4; ++r) {
            int dq = deg_out[mb + r];
            nsr[r] = rsqrtf((float)(dq > 1 ? dq : 1));
        }
        unsigned short* Out = (unsigned short*)OutP;
        #pragma unroll
        for (int t = 0; t < 8; ++t) {
            float bv = bias[t * 16 + l16];
            #pragma unroll
            for (int r = 0; r < 4; ++r) {
                float v = acc[t][r] + bv;
                v = (v > 0.f ? v : 0.f) * nsr[r];
                Out[(size_t)(mb + r) * 128 + t * 16 + l16] = (unsigned short)f2b(v);
            }
        }
    } else {
        float* Out = (float*)OutP;
        #pragma unroll
        for (int t = 0; t < 8; ++t) {
            float bv = bias[t * 16 + l16];
            #pragma unroll
            for (int r = 0; r < 4; ++r) {
                float v = acc[t][r] + bv;
                v = v > 0.f ? v : 0.f;
                Out[(size_t)(mb + r) * 128 + t * 16 + l16] = v;
            }
        }
    }
}

extern "C" void kernel_launch(void* const* d_in, const int* in_sizes, int n_in,
                              void* d_out, int out_size, void* d_ws, size_t ws_size,
                              hipStream_t stream) {
    const float* x  = (const float*)d_in[0];
    const int* src  = (const int*)d_in[1];
    const int* dst  = (const int*)d_in[2];
    const float* Wi = (const float*)d_in[3];
    const float* W1 = (const float*)d_in[4];
    const float* b1 = (const float*)d_in[5];
    const float* W2 = (const float*)d_in[6];
    const float* b2 = (const float*)d_in[7];
    const float* W3 = (const float*)d_in[8];
    const float* b3 = (const float*)d_in[9];

    char* ws = (char*)d_ws;
    int* deg_out   = (int*)(ws + OFF_DEG_OUT);
    int* cursor    = (int*)(ws + OFF_CURSOR);   // becomes deg_in
    unsigned short* Wt  = (unsigned short*)(ws + OFF_WT);
    unsigned short* Wti = (unsigned short*)(ws + OFF_WTI);
    int* bucket    = (int*)(ws + OFF_BUCKET);
    unsigned short* hnA = (unsigned short*)(ws + OFF_HN);
    unsigned short* hnB = (unsigned short*)d_out;   // bf16 ping buffer inside d_out

    hipMemsetAsync(ws, 0, 0x100000, stream);        // zero deg_out + cursor
    k_fill<<<NE / 256, 256, 0, stream>>>(src, dst, deg_out, cursor, bucket);
    k_wprep<<<240, 256, 0, stream>>>(W1, W2, W3, Wi, Wt, Wti);
    k_init<<<NN / 64, 256, 0, stream>>>(x, Wti, deg_out, hnA);

    const float* bl[3] = {b1, b2, b3};
    // ping-pong: L0 hnA->hnB(bf16), L1 hnB->hnA, L2 hnA->d_out(fp32)
    k_layer<<<NN / 64, 256, 0, stream>>>((const uint4*)hnA, bucket, cursor, deg_out,
                                         Wt,         bl[0], (void*)hnB, 0);
    k_layer<<<NN / 64, 256, 0, stream>>>((const uint4*)hnB, bucket, cursor, deg_out,
                                         Wt + 16384, bl[1], (void*)hnA, 0);
    k_layer<<<NN / 64, 256, 0, stream>>>((const uint4*)hnA, bucket, cursor, deg_out,
                                         Wt + 32768, bl[2], d_out, 1);
}

// Round 6
// 445.292 us; speedup vs baseline: 1.6987x; 1.1428x over previous
//
#include <hip/hip_runtime.h>

#define NN 131072   // total nodes (256 graphs x 512)
#define NE 1048576  // edges
// ws layout (bytes); total = 0x4200000 (~69 MB)
#define OFF_DEG_OUT 0x000000   // int[NN]
#define OFF_CURSOR  0x080000   // int[NN] -> becomes deg_in
#define OFF_WT      0x100000   // bf16 3x[128][128] transposed layer weights (96 KB)
#define OFF_WTI     0x118000   // bf16 [128][96] transposed init weight, K-padded (24 KB)
#define OFF_BUCKET  0x200000   // int[NN][64] adjacency buckets (33.5 MB)
#define OFF_HN      0x2200000  // bf16[NN][128] (33.5 MB)

typedef __attribute__((ext_vector_type(8))) short bf16x8;
typedef __attribute__((ext_vector_type(4))) float f32x4;

static __device__ __forceinline__ float blo(unsigned u){ return __uint_as_float(u << 16); }
static __device__ __forceinline__ float bhi(unsigned u){ return __uint_as_float(u & 0xffff0000u); }
static __device__ __forceinline__ unsigned f2b(float f){
    unsigned u = __float_as_uint(f);
    return (u + 0x7fffu + ((u >> 16) & 1u)) >> 16;   // round-to-nearest-even
}
static __device__ __forceinline__ unsigned pack2(float a, float b){
    return f2b(a) | (f2b(b) << 16);
}

// deg_out count + bucketed CSR build; 2 edges/thread, atomics grouped for MLP
__global__ __launch_bounds__(256) void k_fill(const int* __restrict__ src,
                                              const int* __restrict__ dst,
                                              int* __restrict__ deg_out,
                                              int* __restrict__ cursor,
                                              int* __restrict__ bucket) {
    int base = (blockIdx.x * 256 + threadIdx.x) * 2;
    int2 s2 = *(const int2*)&src[base];
    int2 d2 = *(const int2*)&dst[base];
    int p0 = atomicAdd(&cursor[d2.x], 1);
    int p1 = atomicAdd(&cursor[d2.y], 1);
    atomicAdd(&deg_out[s2.x], 1);
    atomicAdd(&deg_out[s2.y], 1);
    if (p0 < 64) bucket[(size_t)d2.x * 64 + p0] = s2.x;   // deg>=64 has P~1e-40
    if (p1 < 64) bucket[(size_t)d2.y * 64 + p1] = s2.y;
}

// all weight transposes in one launch: Wt[L][n][k] (layers) + Wti[n][k0..95] (init, K-padded)
__global__ __launch_bounds__(256) void k_wprep(const float* __restrict__ W1,
                                               const float* __restrict__ W2,
                                               const float* __restrict__ W3,
                                               const float* __restrict__ Wi,
                                               unsigned short* __restrict__ Wt,
                                               unsigned short* __restrict__ Wti) {
    int idx = blockIdx.x * 256 + threadIdx.x;
    if (idx < 49152) {
        int L = idx >> 14, rem = idx & 16383;
        int k = rem >> 7, n = rem & 127;
        const float* W = L == 0 ? W1 : (L == 1 ? W2 : W3);
        Wt[L * 16384 + n * 128 + k] = (unsigned short)f2b(W[k * 128 + n]);
    } else if (idx < 61440) {
        int rem = idx - 49152;
        int n = rem / 96, k = rem - n * 96;
        float v = (k < 74) ? Wi[k * 128 + n] : 0.f;
        Wti[n * 96 + k] = (unsigned short)f2b(v);
    }
}

// hn0 = bf16((x @ W_init) * deg_out^-1/2) via MFMA; X staged+quantized in LDS, K->96
__global__ __launch_bounds__(256) void k_init(const float* __restrict__ X,
                                              const unsigned short* __restrict__ Wti,
                                              const int* __restrict__ deg_out,
                                              unsigned short* __restrict__ hn) {
    __shared__ unsigned int xs[64 * 68];   // 17.4 KB; staging + epilogue reuse
    int tid = threadIdx.x;
    int m0 = blockIdx.x * 64;

    for (int idx = tid; idx < 2368; idx += 256) {        // X: 64 rows x 37 float2, quantize
        int m = idx / 37, t = idx - m * 37;
        float2 v = *(const float2*)&X[(size_t)(m0 + m) * 74 + t * 2];
        xs[m * 68 + t] = pack2(v.x, v.y);
    }
    for (int idx = tid; idx < 64 * 11; idx += 256) {     // zero pad words 37..47 (K 74..95)
        int m = idx / 11, c = 37 + idx % 11;
        xs[m * 68 + c] = 0u;
    }
    __syncthreads();

    int wave = tid >> 6, lane = tid & 63, quad = lane >> 4, l16 = lane & 15;
    f32x4 acc[8];
    #pragma unroll
    for (int t = 0; t < 8; ++t) acc[t] = (f32x4){0.f, 0.f, 0.f, 0.f};
    int arow = (wave * 16 + l16) * 68 + quad * 4;
    #pragma unroll
    for (int ks = 0; ks < 3; ++ks) {
        bf16x8 af = *(const bf16x8*)&xs[arow + ks * 16];
        #pragma unroll
        for (int t = 0; t < 8; ++t) {
            bf16x8 bf = *(const bf16x8*)(Wti + (t * 16 + l16) * 96 + ks * 32 + quad * 8);
            acc[t] = __builtin_amdgcn_mfma_f32_16x16x32_bf16(af, bf, acc[t], 0, 0, 0);
        }
    }
    __syncthreads();   // done reading xs; reuse as bf16 epilogue tile [64][136 shorts]
    unsigned short* atb = (unsigned short*)xs;
    int mb = wave * 16 + quad * 4;
    float nsr[4];
    #pragma unroll
    for (int r = 0; r < 4; ++r) {
        int dq = deg_out[m0 + mb + r];
        nsr[r] = rsqrtf((float)(dq > 1 ? dq : 1));
    }
    #pragma unroll
    for (int t = 0; t < 8; ++t)
        #pragma unroll
        for (int r = 0; r < 4; ++r)
            atb[(mb + r) * 136 + t * 16 + l16] = (unsigned short)f2b(acc[t][r] * nsr[r]);
    __syncthreads();
    {   // coalesced write-out: thread -> row tid>>2, 64-B slice (tid&3)
        int r = tid >> 2, c0 = (tid & 3) * 32;
        unsigned int* sp = &xs[r * 68 + (tid & 3) * 16];
        #pragma unroll
        for (int j = 0; j < 4; ++j)
            *(uint4*)(hn + (size_t)(m0 + r) * 128 + c0 + j * 8) = *(const uint4*)(sp + j * 4);
    }
}

// fused layer: branch-free unroll-8 gather into LDS bf16 A-tile, MFMA vs global Wt
__global__ __launch_bounds__(256) void k_layer(const uint4* __restrict__ hn4,
                                               const int* __restrict__ bucket,
                                               const int* __restrict__ deg_in,
                                               const int* __restrict__ deg_out,
                                               const unsigned short* __restrict__ Wt,
                                               const float* __restrict__ bias,
                                               void* __restrict__ OutP, int last) {
    __shared__ unsigned int at[64 * 68];   // 17.4 KB bf16 A-tile, row stride 68 words
    int tid = threadIdx.x;
    int m0 = blockIdx.x * 64;

    // phase 1: gather 64 node rows; 16 lanes/node (uint4 = 16 B each), 4 passes
    int g = tid >> 4, l16p = tid & 15;
    #pragma unroll
    for (int pass = 0; pass < 4; ++pass) {
        int nl = pass * 16 + g;
        int n = m0 + nl;
        int cnt = deg_in[n];
        cnt = cnt < 64 ? cnt : 64;
        const int* brow = bucket + (size_t)n * 64;
        float a0 = 0, a1 = 0, a2 = 0, a3 = 0, a4 = 0, a5 = 0, a6 = 0, a7 = 0;
        for (int c = 0; c < cnt; c += 8) {
            int4 sA = *(const int4*)&brow[c];
            int4 sB = *(const int4*)&brow[c + 4];
            int lim = cnt - c;
            // branch-free: clamp indices to 0, weight-select accumulate
            int i1 = lim > 1 ? sA.y : 0;
            int i2 = lim > 2 ? sA.z : 0;
            int i3 = lim > 3 ? sA.w : 0;
            int i4 = lim > 4 ? sB.x : 0;
            int i5 = lim > 5 ? sB.y : 0;
            int i6 = lim > 6 ? sB.z : 0;
            int i7 = lim > 7 ? sB.w : 0;
            uint4 v0 = hn4[(size_t)sA.x * 16 + l16p];
            uint4 v1 = hn4[(size_t)i1 * 16 + l16p];
            uint4 v2 = hn4[(size_t)i2 * 16 + l16p];
            uint4 v3 = hn4[(size_t)i3 * 16 + l16p];
            uint4 v4 = hn4[(size_t)i4 * 16 + l16p];
            uint4 v5 = hn4[(size_t)i5 * 16 + l16p];
            uint4 v6 = hn4[(size_t)i6 * 16 + l16p];
            uint4 v7 = hn4[(size_t)i7 * 16 + l16p];
            float w1 = lim > 1 ? 1.f : 0.f;
            float w2 = lim > 2 ? 1.f : 0.f;
            float w3 = lim > 3 ? 1.f : 0.f;
            float w4 = lim > 4 ? 1.f : 0.f;
            float w5 = lim > 5 ? 1.f : 0.f;
            float w6 = lim > 6 ? 1.f : 0.f;
            float w7 = lim > 7 ? 1.f : 0.f;
            a0 += blo(v0.x); a1 += bhi(v0.x); a2 += blo(v0.y); a3 += bhi(v0.y);
            a4 += blo(v0.z); a5 += bhi(v0.z); a6 += blo(v0.w); a7 += bhi(v0.w);
            a0 = fmaf(w1, blo(v1.x), a0); a1 = fmaf(w1, bhi(v1.x), a1);
            a2 = fmaf(w1, blo(v1.y), a2); a3 = fmaf(w1, bhi(v1.y), a3);
            a4 = fmaf(w1, blo(v1.z), a4); a5 = fmaf(w1, bhi(v1.z), a5);
            a6 = fmaf(w1, blo(v1.w), a6); a7 = fmaf(w1, bhi(v1.w), a7);
            a0 = fmaf(w2, blo(v2.x), a0); a1 = fmaf(w2, bhi(v2.x), a1);
            a2 = fmaf(w2, blo(v2.y), a2); a3 = fmaf(w2, bhi(v2.y), a3);
            a4 = fmaf(w2, blo(v2.z), a4); a5 = fmaf(w2, bhi(v2.z), a5);
            a6 = fmaf(w2, blo(v2.w), a6); a7 = fmaf(w2, bhi(v2.w), a7);
            a0 = fmaf(w3, blo(v3.x), a0); a1 = fmaf(w3, bhi(v3.x), a1);
            a2 = fmaf(w3, blo(v3.y), a2); a3 = fmaf(w3, bhi(v3.y), a3);
            a4 = fmaf(w3, blo(v3.z), a4); a5 = fmaf(w3, bhi(v3.z), a5);
            a6 = fmaf(w3, blo(v3.w), a6); a7 = fmaf(w3, bhi(v3.w), a7);
            a0 = fmaf(w4, blo(v4.x), a0); a1 = fmaf(w4, bhi(v4.x), a1);
            a2 = fmaf(w4, blo(v4.y), a2); a3 = fmaf(w4, bhi(v4.y), a3);
            a4 = fmaf(w4, blo(v4.z), a4); a5 = fmaf(w4, bhi(v4.z), a5);
            a6 = fmaf(w4, blo(v4.w), a6); a7 = fmaf(w4, bhi(v4.w), a7);
            a0 = fmaf(w5, blo(v5.x), a0); a1 = fmaf(w5, bhi(v5.x), a1);
            a2 = fmaf(w5, blo(v5.y), a2); a3 = fmaf(w5, bhi(v5.y), a3);
            a4 = fmaf(w5, blo(v5.z), a4); a5 = fmaf(w5, bhi(v5.z), a5);
            a6 = fmaf(w5, blo(v5.w), a6); a7 = fmaf(w5, bhi(v5.w), a7);
            a0 = fmaf(w6, blo(v6.x), a0); a1 = fmaf(w6, bhi(v6.x), a1);
            a2 = fmaf(w6, blo(v6.y), a2); a3 = fmaf(w6, bhi(v6.y), a3);
            a4 = fmaf(w6, blo(v6.z), a4); a5 = fmaf(w6, bhi(v6.z), a5);
            a6 = fmaf(w6, blo(v6.w), a6); a7 = fmaf(w6, bhi(v6.w), a7);
            a0 = fmaf(w7, blo(v7.x), a0); a1 = fmaf(w7, bhi(v7.x), a1);
            a2 = fmaf(w7, blo(v7.y), a2); a3 = fmaf(w7, bhi(v7.y), a3);
            a4 = fmaf(w7, blo(v7.z), a4); a5 = fmaf(w7, bhi(v7.z), a5);
            a6 = fmaf(w7, blo(v7.w), a6); a7 = fmaf(w7, bhi(v7.w), a7);
        }
        float nd = rsqrtf((float)(cnt > 1 ? cnt : 1));
        uint4 o;
        o.x = pack2(a0 * nd, a1 * nd); o.y = pack2(a2 * nd, a3 * nd);
        o.z = pack2(a4 * nd, a5 * nd); o.w = pack2(a6 * nd, a7 * nd);
        *(uint4*)&at[nl * 68 + l16p * 4] = o;
    }
    __syncthreads();

    // phase 2: MFMA 64x128; B-frags straight from global Wt (L2-hot, 32 KB)
    f32x4 acc[8];
    #pragma unroll
    for (int t = 0; t < 8; ++t) acc[t] = (f32x4){0.f, 0.f, 0.f, 0.f};
    int wave = tid >> 6, lane = tid & 63, quad = lane >> 4, l16 = lane & 15;
    int arow = (wave * 16 + l16) * 68 + quad * 4;
    #pragma unroll
    for (int ks = 0; ks < 4; ++ks) {
        bf16x8 af = *(const bf16x8*)&at[arow + ks * 16];
        #pragma unroll
        for (int t = 0; t < 8; ++t) {
            bf16x8 bf = *(const bf16x8*)(Wt + (t * 16 + l16) * 128 + ks * 32 + quad * 8);
            acc[t] = __builtin_amdgcn_mfma_f32_16x16x32_bf16(af, bf, acc[t], 0, 0, 0);
        }
    }

    int mb = wave * 16 + quad * 4;
    if (!last) {
        // bf16 out: LDS transpose (reuse A-tile) -> coalesced uint4 stores
        float nsr[4];
        #pragma unroll
        for (int r = 0; r < 4; ++r) {
            int dq = deg_out[m0 + mb + r];
            nsr[r] = rsqrtf((float)(dq > 1 ? dq : 1));
        }
        __syncthreads();   // all waves done reading A-tile
        unsigned short* atb = (unsigned short*)at;
        #pragma unroll
        for (int t = 0; t < 8; ++t) {
            float bv = bias[t * 16 + l16];
            #pragma unroll
            for (int r = 0; r < 4; ++r) {
                float v = acc[t][r] + bv;
                v = (v > 0.f ? v : 0.f) * nsr[r];
                atb[(mb + r) * 136 + t * 16 + l16] = (unsigned short)f2b(v);
            }
        }
        __syncthreads();
        int r = tid >> 2, c0 = (tid & 3) * 32;
        unsigned short* Out = (unsigned short*)OutP;
        unsigned int* sp = &at[r * 68 + (tid & 3) * 16];
        #pragma unroll
        for (int j = 0; j < 4; ++j)
            *(uint4*)(Out + (size_t)(m0 + r) * 128 + c0 + j * 8) = *(const uint4*)(sp + j * 4);
    } else {
        // fp32 out: direct C-layout stores are full 64-B sectors (16 lanes x 4 B)
        float* Out = (float*)OutP;
        #pragma unroll
        for (int t = 0; t < 8; ++t) {
            float bv = bias[t * 16 + l16];
            #pragma unroll
            for (int r = 0; r < 4; ++r) {
                float v = acc[t][r] + bv;
                v = v > 0.f ? v : 0.f;
                Out[(size_t)(m0 + mb + r) * 128 + t * 16 + l16] = v;
            }
        }
    }
}

extern "C" void kernel_launch(void* const* d_in, const int* in_sizes, int n_in,
                              void* d_out, int out_size, void* d_ws, size_t ws_size,
                              hipStream_t stream) {
    const float* x  = (const float*)d_in[0];
    const int* src  = (const int*)d_in[1];
    const int* dst  = (const int*)d_in[2];
    const float* Wi = (const float*)d_in[3];
    const float* W1 = (const float*)d_in[4];
    const float* b1 = (const float*)d_in[5];
    const float* W2 = (const float*)d_in[6];
    const float* b2 = (const float*)d_in[7];
    const float* W3 = (const float*)d_in[8];
    const float* b3 = (const float*)d_in[9];

    char* ws = (char*)d_ws;
    int* deg_out   = (int*)(ws + OFF_DEG_OUT);
    int* cursor    = (int*)(ws + OFF_CURSOR);   // becomes deg_in
    unsigned short* Wt  = (unsigned short*)(ws + OFF_WT);
    unsigned short* Wti = (unsigned short*)(ws + OFF_WTI);
    int* bucket    = (int*)(ws + OFF_BUCKET);
    unsigned short* hnA = (unsigned short*)(ws + OFF_HN);
    unsigned short* hnB = (unsigned short*)d_out;   // bf16 ping buffer inside d_out

    hipMemsetAsync(ws, 0, 0x100000, stream);        // zero deg_out + cursor
    k_fill<<<NE / 512, 256, 0, stream>>>(src, dst, deg_out, cursor, bucket);
    k_wprep<<<240, 256, 0, stream>>>(W1, W2, W3, Wi, Wt, Wti);
    k_init<<<NN / 64, 256, 0, stream>>>(x, Wti, deg_out, hnA);

    const float* bl[3] = {b1, b2, b3};
    // ping-pong: L0 hnA->hnB(bf16), L1 hnB->hnA, L2 hnA->d_out(fp32)
    k_layer<<<NN / 64, 256, 0, stream>>>((const uint4*)hnA, bucket, cursor, deg_out,
                                         Wt,         bl[0], (void*)hnB, 0);
    k_layer<<<NN / 64, 256, 0, stream>>>((const uint4*)hnB, bucket, cursor, deg_out,
                                         Wt + 16384, bl[1], (void*)hnA, 0);
    k_layer<<<NN / 64, 256, 0, stream>>>((const uint4*)hnA, bucket, cursor, deg_out,
                                         Wt + 32768, bl[2], d_out, 1);
}